// Round 17
// baseline (111.075 us; speedup 1.0000x reference)
//
#include <hip/hip_runtime.h>
#include <math.h>

#define N_    32
#define CIN   128
#define H_    56
#define W_    56
#define COUT  256
#define OH    28
#define OW    28
#define M_    (N_ * OH * OW)      // 25088
#define OUTSZ (M_ * COUT)         // 6,422,528
#define EPS_  0.007f

typedef unsigned short U16;
typedef float f32x4  __attribute__((ext_vector_type(4)));
typedef short bf16x8 __attribute__((ext_vector_type(8)));

// ws float-region layout
#define SCALE_IDX 0
#define ZERO_IDX  8             // wsf[8..15]: 32B zero page for OOB global_load_lds
#define WSQ_IDX   16            // 256 floats
#define U16_BYTE_OFF 102400     // = 25600 floats, 256B aligned

__device__ __forceinline__ U16 f2bf(float f) {
    unsigned int u = __builtin_bit_cast(unsigned int, f);
    u = (u + 0x7fffu + ((u >> 16) & 1u)) >> 16;   // RNE
    return (U16)u;
}
__device__ __forceinline__ float b2f(U16 h) {
    unsigned int u = ((unsigned int)h) << 16;
    return __builtin_bit_cast(float, u);
}

__device__ __forceinline__ void gl_lds16(const U16* g, U16* l) {
    __builtin_amdgcn_global_load_lds((const __attribute__((address_space(1))) void*)g,
                                     (__attribute__((address_space(3))) void*)l, 16, 0, 0);
}

// ---------------- fused prep (+ per-pixel sum-of-squares s2) ----------------
__global__ void k_prep(const float* __restrict__ x,
                       const float* __restrict__ w_yat,
                       const float* __restrict__ w_lin,
                       const float* __restrict__ w_short,
                       const float* __restrict__ alpha,
                       U16* __restrict__ xt, U16* __restrict__ B1,
                       U16* __restrict__ B3, U16* __restrict__ B2,
                       float* __restrict__ wsf, float* __restrict__ s2) {
    int b = blockIdx.x, t = threadIdx.x;
    if (b < 1568) {                                // 32 n x 49 hw-tiles of 64
        __shared__ U16 tile[64 * 130];             // [hw][ci], pad 130
        int n = b / 49, hw0 = (b - n * 49) * 64;
        const float* xb = x + (size_t)n * 128 * 3136 + hw0;
#pragma unroll
        for (int it = 0; it < 32; ++it) {
            int u = it * 256 + t;
            int ci = u >> 6, col = u & 63;
            tile[col * 130 + ci] = f2bf(xb[(size_t)ci * 3136 + col]);
        }
        __syncthreads();
        U16* xo = xt + (size_t)(n * 3136 + hw0) * 128;
#pragma unroll
        for (int it = 0; it < 4; ++it) {
            int u = it * 256 + t;
            int hwl = u >> 4, part = u & 15;
            const U16* src = &tile[hwl * 130 + part * 8];
            unsigned w0 = *(const unsigned*)&src[0];
            unsigned w1 = *(const unsigned*)&src[2];
            unsigned w2 = *(const unsigned*)&src[4];
            unsigned w3 = *(const unsigned*)&src[6];
            uint4 o = {w0, w1, w2, w3};
            *(uint4*)&xo[(size_t)hwl * 128 + part * 8] = o;
        }
        // s2: per-pixel sum of squares (bf16-rounded, matches A fragments)
        if (t < 128) {
            int row = t >> 1, half = t & 1;
            const U16* rp = &tile[row * 130 + half * 64];
            float s = 0.f;
#pragma unroll
            for (int i = 0; i < 32; ++i) {
                unsigned v = *(const unsigned*)&rp[i * 2];
                float f0 = b2f((U16)(v & 0xffff)), f1 = b2f((U16)(v >> 16));
                s += f0 * f0 + f1 * f1;
            }
            s += __shfl_xor(s, 1);
            if (half == 0) s2[(size_t)n * 3136 + hw0 + row] = s;
        }
    } else if (b < 5152) {
        int idx = (b - 1568) * 256 + t;            // 917,504 exactly
        if (idx < 294912) {
            int co = idx / 1152, k = idx % 1152;
            int khkw = k >> 7, ci = k & 127;
            B1[idx] = f2bf(w_yat[(co * 128 + ci) * 9 + khkw]);
        } else if (idx < 294912 + 589824) {
            int i2 = idx - 294912;
            int co = i2 / 2304, k = i2 % 2304;
            int khkw = k >> 8, cy = k & 255;
            B3[i2] = f2bf(w_lin[(co * 256 + cy) * 9 + khkw]);
        } else {
            int i3 = idx - (294912 + 589824);      // < 32768
            B2[i3] = f2bf(w_short[i3]);
        }
    } else {
        int co = b - 5152, lane = t & 63, wv = t >> 6;
        const float* wc = w_yat + (size_t)co * 1152;
        float s = 0.f;
        for (int i = t; i < 1152; i += 256) { float v = wc[i]; s += v * v; }
#pragma unroll
        for (int off = 32; off >= 1; off >>= 1) s += __shfl_xor(s, off);
        __shared__ float red[4];
        if (lane == 0) red[wv] = s;
        __syncthreads();
        if (t == 0) {
            wsf[WSQ_IDX + co] = red[0] + red[1] + red[2] + red[3];
            if (co == 0) wsf[SCALE_IDX] = powf(16.0f / log1pf(256.0f), alpha[0]);
        }
        if (co == 0 && t >= 8 && t < 16) wsf[ZERO_IDX + (t - 8)] = 0.f;
    }
}

// ---------------- k_yat: BM=128 BN=64 BK=128, 48 KB LDS -> 3 blocks/CU ----------------
// psq from s2 table in prologue; fused 1x1 shortcut at center tap.
// grid 784 = 8*98 (bijective XCD swizzle). 4 waves as 2x2 -> wave tile 64x32 (i=4, j=2).
__launch_bounds__(256, 3)
__global__ void k_yat(const U16* __restrict__ xt, const U16* __restrict__ B1,
                      const U16* __restrict__ B2p, const float* __restrict__ wsf,
                      const float* __restrict__ s2,
                      U16* __restrict__ ybuf, U16* __restrict__ pid) {
    __shared__ U16 Ab[128 * 128];                  // 32 KB
    __shared__ U16 Bb[64 * 128];                   // 16 KB
    __shared__ float psq_s[128];

    int t = threadIdx.x, lane = t & 63, wv = t >> 6;
    int wr = wv >> 1, wc = wv & 1;                 // wave tile: rows wr*64 (4 frags), cols wc*32 (2 frags)
    int bid = blockIdx.x;                          // 784 = 8*98
    int logical = (bid & 7) * 98 + (bid >> 3);
    int m0 = (logical >> 2) * 128;
    int co_base = (logical & 3) * 64;

    // ---- prologue: psq from s2 ----
    if (t < 128) {
        int m = m0 + t;
        int tt = m / 28; int ow = m - tt * 28; int n = tt / 28; int oh = tt - n * 28;
        const float* s2b = s2 + (size_t)n * 3136;
        float s = 0.f;
#pragma unroll
        for (int kh = 0; kh < 3; ++kh) {
            int ih = oh * 2 - 1 + kh;
            if ((unsigned)ih >= 56) continue;
#pragma unroll
            for (int kw = 0; kw < 3; ++kw) {
                int iw = ow * 2 - 1 + kw;
                if ((unsigned)iw >= 56) continue;
                s += s2b[ih * 56 + iw];
            }
        }
        psq_s[t] = s;
    }

    const U16* zptr = (const U16*)&wsf[ZERO_IDX];

    // A-staging: 128 rows x 16 units -> 8 rounds
    int arow0 = t >> 4, apart = t & 15;
    int plog  = apart ^ (arow0 & 15);
    int an[8], aoh[8], aow[8];
#pragma unroll
    for (int q = 0; q < 8; ++q) {
        int am = m0 + arow0 + 16 * q;
        int tt = am / 28; aow[q] = am - tt * 28; an[q] = tt / 28; aoh[q] = tt - an[q] * 28;
    }

    f32x4 acc[4][2] = {};
    f32x4 acc2[4][2] = {};

    for (int kq = 0; kq < 9; ++kq) {
        int kh = kq / 3, kw = kq - 3 * kh;
        // ---- stage A [128 m][128 ci] ----
#pragma unroll
        for (int q = 0; q < 8; ++q) {
            int ih = aoh[q] * 2 - 1 + kh, iw = aow[q] * 2 - 1 + kw;
            bool v = ((unsigned)ih < 56) & ((unsigned)iw < 56);
            const U16* sp = v ? xt + ((size_t)((an[q] * 56 + ih) * 56 + iw) << 7) + plog * 8 : zptr;
            gl_lds16(sp, &Ab[(size_t)(q * 256 + t) * 8]);
        }
        // ---- stage B [64 co][128 ci] : 4 rounds ----
#pragma unroll
        for (int q = 0; q < 4; ++q) {
            int u = q * 256 + t;
            int brow = u >> 4, bpart = u & 15;
            int bplog = bpart ^ (brow & 15);
            const U16* sp = B1 + (size_t)(co_base + brow) * 1152 + kq * 128 + bplog * 8;
            gl_lds16(sp, &Bb[(size_t)u * 8]);
        }
        __syncthreads();
#pragma unroll
        for (int kk = 0; kk < 4; ++kk) {
            bf16x8 au[4], bu[2];
#pragma unroll
            for (int i = 0; i < 4; ++i) {
                int row = wr * 64 + i * 16 + (lane & 15);
                int pp = (kk * 4 + (lane >> 4)) ^ (row & 15);
                au[i] = *(const bf16x8*)&Ab[(row * 16 + pp) * 8];
            }
#pragma unroll
            for (int j = 0; j < 2; ++j) {
                int col = wc * 32 + j * 16 + (lane & 15);
                int pp = (kk * 4 + (lane >> 4)) ^ (col & 15);
                bu[j] = *(const bf16x8*)&Bb[(col * 16 + pp) * 8];
            }
#pragma unroll
            for (int i = 0; i < 4; ++i)
#pragma unroll
                for (int j = 0; j < 2; ++j)
                    acc[i][j] = __builtin_amdgcn_mfma_f32_16x16x32_bf16(au[i], bu[j], acc[i][j], 0, 0, 0);
            if (kq == 4) {                         // center tap: fused 1x1 shortcut
#pragma unroll
                for (int j = 0; j < 2; ++j) {
                    int col = wc * 32 + j * 16 + (lane & 15);
                    int qp = kk * 4 + (lane >> 4);
                    bf16x8 b2v = *(const bf16x8*)&B2p[(size_t)(co_base + col) * 128 + qp * 8];
#pragma unroll
                    for (int i = 0; i < 4; ++i)
                        acc2[i][j] = __builtin_amdgcn_mfma_f32_16x16x32_bf16(au[i], b2v, acc2[i][j], 0, 0, 0);
                }
            }
        }
        __syncthreads();
    }

    float scale = wsf[SCALE_IDX];
#pragma unroll
    for (int i = 0; i < 4; ++i)
#pragma unroll
        for (int j = 0; j < 2; ++j)
#pragma unroll
            for (int r = 0; r < 4; ++r) {
                int row = wr * 64 + i * 16 + ((lane >> 4) << 2) + r;
                int coll = wc * 32 + j * 16 + (lane & 15);
                int m = m0 + row;
                int co = co_base + coll;
                size_t oidx = (size_t)m * 256 + co;
                float dot = acc[i][j][r];
                float dist = psq_s[row] + wsf[WSQ_IDX + co] - 2.0f * dot + EPS_;
                float y = dot * dot / dist * scale;
                ybuf[oidx] = f2bf(y);
                pid[oidx]  = f2bf(acc2[i][j][r]);
            }
}

// ---------------- k_lin<NS>: 3x3 s1 p1 conv, A-halo LDS + LDS-staged B, ci 1/NS split ----
template<int NS>
__launch_bounds__(256, NS)
__global__ void k_lin(const U16* __restrict__ yb, const U16* __restrict__ B3,
                      U16* __restrict__ pA, U16* __restrict__ pB) {
    constexpr int CIW  = 256 / NS;                 // 64 or 128
    constexpr int PRTS = CIW / 8;                  // 8 or 16
    constexpr int PMSK = PRTS - 1;
    constexpr int NKK  = CIW / 32;                 // 2 or 4

    __shared__ U16 Ah[192 * CIW];
    __shared__ U16 Bt[128 * CIW];

    int t = threadIdx.x, lane = t & 63, wv = t >> 6;
    int wr = wv >> 1, wc = wv & 1;
    int bid = blockIdx.x;                          // NS*392
    int s = bid / 392;
    int inner = bid - 392 * s;
    int co_sel = (inner >= 196) ? 1 : 0;
    int mt = inner - 196 * co_sel;
    int xcd = mt & 7, pos = mt >> 3;               // m204 bijective swizzle (q=24, r=4)
    int swz = (xcd < 4 ? xcd * 25 : 100 + (xcd - 4) * 24) + pos;
    int m0 = swz * 128;
    int co_base = co_sel * 128;
    int kci = s * CIW;

    // ---- stage A halo once: 192 rows x CIW ci ----
#pragma unroll
    for (int q = 0; q < (192 * PRTS) / 256; ++q) { // 6 or 12 rounds
        int u = q * 256 + t;
        int row = u / PRTS, part = u & PMSK;
        int plog = part ^ (row & PMSK);
        int mm = m0 - 32 + row;
        mm = mm < 0 ? 0 : (mm >= M_ ? M_ - 1 : mm);
        gl_lds16(yb + (size_t)mm * 256 + kci + plog * 8, &Ah[(size_t)u * 8]);
    }

    // B staging coords
    int brow = t / PRTS, bpart = t & PMSK;
    int bplog = bpart ^ (brow & PMSK);

    // per-i row coords + validity precompute
    int mrow[4], owv[4], ohv[4];
#pragma unroll
    for (int i = 0; i < 4; ++i) {
        mrow[i] = wr * 64 + i * 16 + (lane & 15);
        int m = m0 + mrow[i];
        int tt = m / 28; owv[i] = m - tt * 28; ohv[i] = tt % 28;
    }

    f32x4 acc[4][4] = {};
    constexpr int BROWS = 256 / PRTS;              // col coverage per round: 32 or 16

    for (int tap = 0; tap < 9; ++tap) {
        int kh = tap / 3, kw = tap - 3 * kh;
        int dlt = (kh - 1) * 28 + (kw - 1);
        // ---- stage B [128 co][CIW] for this tap ----
#pragma unroll
        for (int q = 0; q < (128 * PRTS) / 256; ++q) {   // 4 or 8 rounds
            const U16* sp = B3 + (size_t)(co_base + brow + BROWS * q) * 2304
                               + tap * 256 + kci + bplog * 8;
            gl_lds16(sp, &Bt[(size_t)(q * 256 + t) * 8]);
        }
        __syncthreads();                           // drains halo (tap0) + B

        bool val[4];
#pragma unroll
        for (int i = 0; i < 4; ++i)
            val[i] = ((unsigned)(owv[i] + kw - 1) < 28u) & ((unsigned)(ohv[i] + kh - 1) < 28u);

#pragma unroll
        for (int kk = 0; kk < NKK; ++kk) {
            bf16x8 au[4], bu[4];
#pragma unroll
            for (int i = 0; i < 4; ++i) {
                int ra = mrow[i] + 32 + dlt;       // halo row in [3, 189)
                int pp = (kk * 4 + (lane >> 4)) ^ (ra & PMSK);
                bf16x8 av = *(const bf16x8*)&Ah[(ra * PRTS + pp) * 8];
                bf16x8 z = {};
                au[i] = val[i] ? av : z;
            }
#pragma unroll
            for (int j = 0; j < 4; ++j) {
                int col = wc * 64 + j * 16 + (lane & 15);
                int pp = (kk * 4 + (lane >> 4)) ^ (col & PMSK);
                bu[j] = *(const bf16x8*)&Bt[(col * PRTS + pp) * 8];
            }
#pragma unroll
            for (int i = 0; i < 4; ++i)
#pragma unroll
                for (int j = 0; j < 4; ++j)
                    acc[i][j] = __builtin_amdgcn_mfma_f32_16x16x32_bf16(au[i], bu[j], acc[i][j], 0, 0, 0);
        }
        __syncthreads();                           // Bt reuse next tap (Ah untouched)
    }

    // ---- epilogue: coalesced bf16 partials ----
    U16* pout = (s < 2) ? pA + (size_t)s * OUTSZ : pB + (size_t)(s - 2) * OUTSZ;
#pragma unroll
    for (int i = 0; i < 4; ++i)
#pragma unroll
        for (int j = 0; j < 4; ++j)
#pragma unroll
            for (int r = 0; r < 4; ++r) {
                int row = wr * 64 + i * 16 + ((lane >> 4) << 2) + r;
                int coll = wc * 64 + j * 16 + (lane & 15);
                size_t oidx = (size_t)(m0 + row) * 256 + co_base + coll;
                pout[oidx] = f2bf(acc[i][j][r]);
            }
}

// ---------------- final reduce + transpose (full-cache-line reads) ----------------
template<int NP>
__global__ void k_red(const U16* __restrict__ pid, const U16* __restrict__ p01,
                      const U16* __restrict__ p23, float* __restrict__ out) {
    __shared__ float tile[196 * 65];
    int t = threadIdx.x;
    int b = blockIdx.x;                            // 512 = 32 n * 4 mq * 4 cog
    int n = b >> 4;
    int mq = (b >> 2) & 3;
    int cog = b & 3;
    size_t base = ((size_t)n * 784 + mq * 196) * 256 + cog * 64;

    auto addsrc = [](const U16* p, size_t a, float* r) {
        uint4 v = *(const uint4*)(p + a);          // 8 bf16
        const unsigned* w = (const unsigned*)&v;
#pragma unroll
        for (int e = 0; e < 4; ++e) {
            r[2 * e]     += b2f((U16)(w[e] & 0xffff));
            r[2 * e + 1] += b2f((U16)(w[e] >> 16));
        }
    };

    for (int u = t; u < 196 * 8; u += 256) {       // row = u>>3, 8 co per thread
        int row = u >> 3, part = u & 7;
        size_t a = base + (size_t)row * 256 + part * 8;
        float r[8] = {};
        addsrc(pid, a, r);
        addsrc(p01, a, r);
        addsrc(p01 + (size_t)OUTSZ, a, r);
        if (NP == 4) {
            addsrc(p23, a, r);
            addsrc(p23 + (size_t)OUTSZ, a, r);
        }
        float* dst = &tile[row * 65 + part * 8];
#pragma unroll
        for (int e = 0; e < 8; ++e) dst[e] = r[e];
    }
    __syncthreads();

    for (int u = t; u < 64 * 49; u += 256) {       // co = u/49, m4 = u%49 (float4 along m)
        int co = u / 49, m4 = u - co * 49;
        float4 v = { tile[(m4 * 4 + 0) * 65 + co],
                     tile[(m4 * 4 + 1) * 65 + co],
                     tile[(m4 * 4 + 2) * 65 + co],
                     tile[(m4 * 4 + 3) * 65 + co] };
        *(float4*)(out + ((size_t)(n * 256 + cog * 64 + co) * 784 + mq * 196 + m4 * 4)) = v;
    }
}

extern "C" void kernel_launch(void* const* d_in, const int* in_sizes, int n_in,
                              void* d_out, int out_size, void* d_ws, size_t ws_size,
                              hipStream_t stream) {
    const float* x       = (const float*)d_in[0];
    const float* w_yat   = (const float*)d_in[1];
    const float* alpha   = (const float*)d_in[2];
    const float* w_lin   = (const float*)d_in[3];
    const float* w_short = (const float*)d_in[4];
    float* out = (float*)d_out;
    float* wsf = (float*)d_ws;

    U16* xt  = (U16*)((char*)d_ws + U16_BYTE_OFF);
    U16* yb  = xt + (size_t)N_ * H_ * W_ * CIN;       // 12,845,056 U16 (= 2 x OUTSZ)
    U16* B1  = yb + (size_t)OUTSZ;                    // +6,422,528
    U16* B2  = B1 + 1152 * COUT;                      // +294,912
    U16* B3  = B2 + CIN * COUT;                       // +32,768
    U16* pid = B3 + 2304 * COUT;                      // +589,824
    U16* p23 = pid + (size_t)OUTSZ;                   // +6,422,528 (NS=4 lin partials)
    float* s2 = (float*)p23;                          // 401 KB, dead before k_lin writes p23

    size_t need4 = (size_t)U16_BYTE_OFF +
                   2 * ((size_t)(p23 - xt) + 2 * (size_t)OUTSZ);
    bool four = ws_size >= need4;

    k_prep<<<5408, 256, 0, stream>>>(x, w_yat, w_lin, w_short, alpha, xt, B1, B3, B2, wsf, s2);
    k_yat <<<784, 256, 0, stream>>>(xt, B1, B2, wsf, s2, yb, pid);

    if (four) {
        k_lin<4><<<1568, 256, 0, stream>>>(yb, B3, xt, p23);   // p0,p1 alias xt; p2,p3 = p23
        k_red<4><<<512, 256, 0, stream>>>(pid, xt, p23, out);
    } else {
        k_lin<2><<<784, 256, 0, stream>>>(yb, B3, xt, nullptr);
        k_red<2><<<512, 256, 0, stream>>>(pid, xt, nullptr, out);
    }
}

// Round 18
// 106.513 us; speedup vs baseline: 1.0428x; 1.0428x over previous
//
#include <hip/hip_runtime.h>
#include <math.h>

#define N_    32
#define CIN   128
#define H_    56
#define W_    56
#define COUT  256
#define OH    28
#define OW    28
#define M_    (N_ * OH * OW)      // 25088
#define OUTSZ (M_ * COUT)         // 6,422,528
#define EPS_  0.007f

typedef unsigned short U16;
typedef float f32x4  __attribute__((ext_vector_type(4)));
typedef short bf16x8 __attribute__((ext_vector_type(8)));

// ws float-region layout
#define SCALE_IDX 0
#define ZERO_IDX  8             // wsf[8..15]: 32B zero page for OOB global_load_lds
#define WSQ_IDX   16            // 256 floats
#define U16_BYTE_OFF 102400     // = 25600 floats, 256B aligned

__device__ __forceinline__ U16 f2bf(float f) {
    unsigned int u = __builtin_bit_cast(unsigned int, f);
    u = (u + 0x7fffu + ((u >> 16) & 1u)) >> 16;   // RNE
    return (U16)u;
}
__device__ __forceinline__ float b2f(U16 h) {
    unsigned int u = ((unsigned int)h) << 16;
    return __builtin_bit_cast(float, u);
}

__device__ __forceinline__ void gl_lds16(const U16* g, U16* l) {
    __builtin_amdgcn_global_load_lds((const __attribute__((address_space(1))) void*)g,
                                     (__attribute__((address_space(3))) void*)l, 16, 0, 0);
}

// ---------------- fused prep (+ per-pixel sum-of-squares s2) ----------------
__global__ void k_prep(const float* __restrict__ x,
                       const float* __restrict__ w_yat,
                       const float* __restrict__ w_lin,
                       const float* __restrict__ w_short,
                       const float* __restrict__ alpha,
                       U16* __restrict__ xt, U16* __restrict__ B1,
                       U16* __restrict__ B3, U16* __restrict__ B2,
                       float* __restrict__ wsf, float* __restrict__ s2) {
    int b = blockIdx.x, t = threadIdx.x;
    if (b < 1568) {                                // 32 n x 49 hw-tiles of 64
        __shared__ U16 tile[64 * 130];             // [hw][ci], pad 130
        int n = b / 49, hw0 = (b - n * 49) * 64;
        const float* xb = x + (size_t)n * 128 * 3136 + hw0;
#pragma unroll
        for (int it = 0; it < 32; ++it) {
            int u = it * 256 + t;
            int ci = u >> 6, col = u & 63;
            tile[col * 130 + ci] = f2bf(xb[(size_t)ci * 3136 + col]);
        }
        __syncthreads();
        U16* xo = xt + (size_t)(n * 3136 + hw0) * 128;
#pragma unroll
        for (int it = 0; it < 4; ++it) {
            int u = it * 256 + t;
            int hwl = u >> 4, part = u & 15;
            const U16* src = &tile[hwl * 130 + part * 8];
            unsigned w0 = *(const unsigned*)&src[0];
            unsigned w1 = *(const unsigned*)&src[2];
            unsigned w2 = *(const unsigned*)&src[4];
            unsigned w3 = *(const unsigned*)&src[6];
            uint4 o = {w0, w1, w2, w3};
            *(uint4*)&xo[(size_t)hwl * 128 + part * 8] = o;
        }
        // s2: per-pixel sum of squares (bf16-rounded, matches A fragments)
        if (t < 128) {
            int row = t >> 1, half = t & 1;
            const U16* rp = &tile[row * 130 + half * 64];
            float s = 0.f;
#pragma unroll
            for (int i = 0; i < 32; ++i) {
                unsigned v = *(const unsigned*)&rp[i * 2];
                float f0 = b2f((U16)(v & 0xffff)), f1 = b2f((U16)(v >> 16));
                s += f0 * f0 + f1 * f1;
            }
            s += __shfl_xor(s, 1);
            if (half == 0) s2[(size_t)n * 3136 + hw0 + row] = s;
        }
    } else if (b < 5152) {
        int idx = (b - 1568) * 256 + t;            // 917,504 exactly
        if (idx < 294912) {
            int co = idx / 1152, k = idx % 1152;
            int khkw = k >> 7, ci = k & 127;
            B1[idx] = f2bf(w_yat[(co * 128 + ci) * 9 + khkw]);
        } else if (idx < 294912 + 589824) {
            int i2 = idx - 294912;
            int co = i2 / 2304, k = i2 % 2304;
            int khkw = k >> 8, cy = k & 255;
            B3[i2] = f2bf(w_lin[(co * 256 + cy) * 9 + khkw]);
        } else {
            int i3 = idx - (294912 + 589824);      // < 32768
            B2[i3] = f2bf(w_short[i3]);
        }
    } else {
        int co = b - 5152, lane = t & 63, wv = t >> 6;
        const float* wc = w_yat + (size_t)co * 1152;
        float s = 0.f;
        for (int i = t; i < 1152; i += 256) { float v = wc[i]; s += v * v; }
#pragma unroll
        for (int off = 32; off >= 1; off >>= 1) s += __shfl_xor(s, off);
        __shared__ float red[4];
        if (lane == 0) red[wv] = s;
        __syncthreads();
        if (t == 0) {
            wsf[WSQ_IDX + co] = red[0] + red[1] + red[2] + red[3];
            if (co == 0) wsf[SCALE_IDX] = powf(16.0f / log1pf(256.0f), alpha[0]);
        }
        if (co == 0 && t >= 8 && t < 16) wsf[ZERO_IDX + (t - 8)] = 0.f;
    }
}

// ---------------- k_yat: BM=BN=128 BK=128 (R16 proven shape, grid 392 all-co-resident) ----
// psq from s2 table in prologue; fused 1x1 shortcut at center tap.
__launch_bounds__(256, 2)
__global__ void k_yat(const U16* __restrict__ xt, const U16* __restrict__ B1,
                      const U16* __restrict__ B2p, const float* __restrict__ wsf,
                      const float* __restrict__ s2,
                      U16* __restrict__ ybuf, U16* __restrict__ pid) {
    __shared__ U16 Ab[128 * 128];                  // 32 KB
    __shared__ U16 Bb[128 * 128];                  // 32 KB
    __shared__ float psq_s[128];

    int t = threadIdx.x, lane = t & 63, wv = t >> 6;
    int wr = wv >> 1, wc = wv & 1;
    int bid = blockIdx.x;                          // 392 = 8*49
    int logical = (bid & 7) * 49 + (bid >> 3);
    int m0 = (logical >> 1) * 128;
    int co_base = (logical & 1) * 128;

    // ---- prologue: psq from s2 ----
    if (t < 128) {
        int m = m0 + t;
        int tt = m / 28; int ow = m - tt * 28; int n = tt / 28; int oh = tt - n * 28;
        const float* s2b = s2 + (size_t)n * 3136;
        float s = 0.f;
#pragma unroll
        for (int kh = 0; kh < 3; ++kh) {
            int ih = oh * 2 - 1 + kh;
            if ((unsigned)ih >= 56) continue;
#pragma unroll
            for (int kw = 0; kw < 3; ++kw) {
                int iw = ow * 2 - 1 + kw;
                if ((unsigned)iw >= 56) continue;
                s += s2b[ih * 56 + iw];
            }
        }
        psq_s[t] = s;
    }

    const U16* zptr = (const U16*)&wsf[ZERO_IDX];

    int arow0 = t >> 4, apart = t & 15;
    int plog  = apart ^ (arow0 & 15);
    int an[8], aoh[8], aow[8];
#pragma unroll
    for (int q = 0; q < 8; ++q) {
        int am = m0 + arow0 + 16 * q;
        int tt = am / 28; aow[q] = am - tt * 28; an[q] = tt / 28; aoh[q] = tt - an[q] * 28;
    }

    f32x4 acc[4][4] = {};
    f32x4 acc2[4][4] = {};

    for (int kq = 0; kq < 9; ++kq) {
        int kh = kq / 3, kw = kq - 3 * kh;
#pragma unroll
        for (int q = 0; q < 8; ++q) {
            int ih = aoh[q] * 2 - 1 + kh, iw = aow[q] * 2 - 1 + kw;
            bool v = ((unsigned)ih < 56) & ((unsigned)iw < 56);
            const U16* sp = v ? xt + ((size_t)((an[q] * 56 + ih) * 56 + iw) << 7) + plog * 8 : zptr;
            gl_lds16(sp, &Ab[(size_t)(q * 256 + t) * 8]);
        }
#pragma unroll
        for (int q = 0; q < 8; ++q) {
            const U16* sp = B1 + (size_t)(co_base + arow0 + 16 * q) * 1152 + kq * 128 + plog * 8;
            gl_lds16(sp, &Bb[(size_t)(q * 256 + t) * 8]);
        }
        __syncthreads();
#pragma unroll
        for (int kk = 0; kk < 4; ++kk) {
            bf16x8 au[4], bu[4];
#pragma unroll
            for (int i = 0; i < 4; ++i) {
                int row = wr * 64 + i * 16 + (lane & 15);
                int pp = (kk * 4 + (lane >> 4)) ^ (row & 15);
                au[i] = *(const bf16x8*)&Ab[(row * 16 + pp) * 8];
            }
#pragma unroll
            for (int j = 0; j < 4; ++j) {
                int col = wc * 64 + j * 16 + (lane & 15);
                int pp = (kk * 4 + (lane >> 4)) ^ (col & 15);
                bu[j] = *(const bf16x8*)&Bb[(col * 16 + pp) * 8];
            }
#pragma unroll
            for (int i = 0; i < 4; ++i)
#pragma unroll
                for (int j = 0; j < 4; ++j)
                    acc[i][j] = __builtin_amdgcn_mfma_f32_16x16x32_bf16(au[i], bu[j], acc[i][j], 0, 0, 0);
            if (kq == 4) {                         // center tap: fused 1x1 shortcut
#pragma unroll
                for (int j = 0; j < 4; ++j) {
                    int col = wc * 64 + j * 16 + (lane & 15);
                    int qp = kk * 4 + (lane >> 4);
                    bf16x8 b2v = *(const bf16x8*)&B2p[(size_t)(co_base + col) * 128 + qp * 8];
#pragma unroll
                    for (int i = 0; i < 4; ++i)
                        acc2[i][j] = __builtin_amdgcn_mfma_f32_16x16x32_bf16(au[i], b2v, acc2[i][j], 0, 0, 0);
                }
            }
        }
        __syncthreads();
    }

    float scale = wsf[SCALE_IDX];
#pragma unroll
    for (int i = 0; i < 4; ++i)
#pragma unroll
        for (int j = 0; j < 4; ++j)
#pragma unroll
            for (int r = 0; r < 4; ++r) {
                int row = wr * 64 + i * 16 + ((lane >> 4) << 2) + r;
                int coll = wc * 64 + j * 16 + (lane & 15);
                int m = m0 + row;
                int co = co_base + coll;
                size_t oidx = (size_t)m * 256 + co;
                float dot = acc[i][j][r];
                float dist = psq_s[row] + wsf[WSQ_IDX + co] - 2.0f * dot + EPS_;
                float y = dot * dot / dist * scale;
                ybuf[oidx] = f2bf(y);
                pid[oidx]  = f2bf(acc2[i][j][r]);
            }
}

// ---------------- k_lin<NS>: 3x3 s1 p1 conv, A-halo LDS + LDS-staged B, ci 1/NS split ----
// s==0 blocks fold the identity partial (pid) into their accumulator before writing,
// so k_red reads one fewer source.
template<int NS>
__launch_bounds__(256, NS)
__global__ void k_lin(const U16* __restrict__ yb, const U16* __restrict__ B3,
                      const U16* __restrict__ pid,
                      U16* __restrict__ pA, U16* __restrict__ pB) {
    constexpr int CIW  = 256 / NS;                 // 64 or 128
    constexpr int PRTS = CIW / 8;                  // 8 or 16
    constexpr int PMSK = PRTS - 1;
    constexpr int NKK  = CIW / 32;                 // 2 or 4

    __shared__ U16 Ah[192 * CIW];
    __shared__ U16 Bt[128 * CIW];

    int t = threadIdx.x, lane = t & 63, wv = t >> 6;
    int wr = wv >> 1, wc = wv & 1;
    int bid = blockIdx.x;                          // NS*392
    int s = bid / 392;
    int inner = bid - 392 * s;
    int co_sel = (inner >= 196) ? 1 : 0;
    int mt = inner - 196 * co_sel;
    int xcd = mt & 7, pos = mt >> 3;               // m204 bijective swizzle (q=24, r=4)
    int swz = (xcd < 4 ? xcd * 25 : 100 + (xcd - 4) * 24) + pos;
    int m0 = swz * 128;
    int co_base = co_sel * 128;
    int kci = s * CIW;

    // ---- stage A halo once: 192 rows x CIW ci ----
#pragma unroll
    for (int q = 0; q < (192 * PRTS) / 256; ++q) { // 6 or 12 rounds
        int u = q * 256 + t;
        int row = u / PRTS, part = u & PMSK;
        int plog = part ^ (row & PMSK);
        int mm = m0 - 32 + row;
        mm = mm < 0 ? 0 : (mm >= M_ ? M_ - 1 : mm);
        gl_lds16(yb + (size_t)mm * 256 + kci + plog * 8, &Ah[(size_t)u * 8]);
    }

    // B staging coords
    int brow = t / PRTS, bpart = t & PMSK;
    int bplog = bpart ^ (brow & PMSK);

    // per-i row coords + validity precompute
    int mrow[4], owv[4], ohv[4];
#pragma unroll
    for (int i = 0; i < 4; ++i) {
        mrow[i] = wr * 64 + i * 16 + (lane & 15);
        int m = m0 + mrow[i];
        int tt = m / 28; owv[i] = m - tt * 28; ohv[i] = tt % 28;
    }

    f32x4 acc[4][4] = {};
    constexpr int BROWS = 256 / PRTS;              // col coverage per round: 32 or 16

    for (int tap = 0; tap < 9; ++tap) {
        int kh = tap / 3, kw = tap - 3 * kh;
        int dlt = (kh - 1) * 28 + (kw - 1);
        // ---- stage B [128 co][CIW] for this tap ----
#pragma unroll
        for (int q = 0; q < (128 * PRTS) / 256; ++q) {   // 4 or 8 rounds
            const U16* sp = B3 + (size_t)(co_base + brow + BROWS * q) * 2304
                               + tap * 256 + kci + bplog * 8;
            gl_lds16(sp, &Bt[(size_t)(q * 256 + t) * 8]);
        }
        __syncthreads();                           // drains halo (tap0) + B

        bool val[4];
#pragma unroll
        for (int i = 0; i < 4; ++i)
            val[i] = ((unsigned)(owv[i] + kw - 1) < 28u) & ((unsigned)(ohv[i] + kh - 1) < 28u);

#pragma unroll
        for (int kk = 0; kk < NKK; ++kk) {
            bf16x8 au[4], bu[4];
#pragma unroll
            for (int i = 0; i < 4; ++i) {
                int ra = mrow[i] + 32 + dlt;       // halo row in [3, 189)
                int pp = (kk * 4 + (lane >> 4)) ^ (ra & PMSK);
                bf16x8 av = *(const bf16x8*)&Ah[(ra * PRTS + pp) * 8];
                bf16x8 z = {};
                au[i] = val[i] ? av : z;
            }
#pragma unroll
            for (int j = 0; j < 4; ++j) {
                int col = wc * 64 + j * 16 + (lane & 15);
                int pp = (kk * 4 + (lane >> 4)) ^ (col & PMSK);
                bu[j] = *(const bf16x8*)&Bt[(col * PRTS + pp) * 8];
            }
#pragma unroll
            for (int i = 0; i < 4; ++i)
#pragma unroll
                for (int j = 0; j < 4; ++j)
                    acc[i][j] = __builtin_amdgcn_mfma_f32_16x16x32_bf16(au[i], bu[j], acc[i][j], 0, 0, 0);
        }
        __syncthreads();                           // Bt reuse next tap (Ah untouched)
    }

    // ---- epilogue: coalesced bf16 partials; s==0 folds identity ----
    U16* pout = (s < 2) ? pA + (size_t)s * OUTSZ : pB + (size_t)(s - 2) * OUTSZ;
#pragma unroll
    for (int i = 0; i < 4; ++i)
#pragma unroll
        for (int j = 0; j < 4; ++j)
#pragma unroll
            for (int r = 0; r < 4; ++r) {
                int row = wr * 64 + i * 16 + ((lane >> 4) << 2) + r;
                int coll = wc * 64 + j * 16 + (lane & 15);
                size_t oidx = (size_t)(m0 + row) * 256 + co_base + coll;
                float v = acc[i][j][r];
                if (s == 0) v += b2f(pid[oidx]);
                pout[oidx] = f2bf(v);
            }
}

// ---------------- final reduce + transpose (full-cache-line reads, NP sources) ----------
template<int NP>
__global__ void k_red(const U16* __restrict__ p01, const U16* __restrict__ p23,
                      float* __restrict__ out) {
    __shared__ float tile[196 * 65];
    int t = threadIdx.x;
    int b = blockIdx.x;                            // 512 = 32 n * 4 mq * 4 cog
    int n = b >> 4;
    int mq = (b >> 2) & 3;
    int cog = b & 3;
    size_t base = ((size_t)n * 784 + mq * 196) * 256 + cog * 64;

    auto addsrc = [](const U16* p, size_t a, float* r) {
        uint4 v = *(const uint4*)(p + a);          // 8 bf16
        const unsigned* w = (const unsigned*)&v;
#pragma unroll
        for (int e = 0; e < 4; ++e) {
            r[2 * e]     += b2f((U16)(w[e] & 0xffff));
            r[2 * e + 1] += b2f((U16)(w[e] >> 16));
        }
    };

    for (int u = t; u < 196 * 8; u += 256) {       // row = u>>3, 8 co per thread
        int row = u >> 3, part = u & 7;
        size_t a = base + (size_t)row * 256 + part * 8;
        float r[8] = {};
        addsrc(p01, a, r);
        addsrc(p01 + (size_t)OUTSZ, a, r);
        if (NP == 4) {
            addsrc(p23, a, r);
            addsrc(p23 + (size_t)OUTSZ, a, r);
        }
        float* dst = &tile[row * 65 + part * 8];
#pragma unroll
        for (int e = 0; e < 8; ++e) dst[e] = r[e];
    }
    __syncthreads();

    for (int u = t; u < 64 * 49; u += 256) {       // co = u/49, m4 = u%49 (float4 along m)
        int co = u / 49, m4 = u - co * 49;
        float4 v = { tile[(m4 * 4 + 0) * 65 + co],
                     tile[(m4 * 4 + 1) * 65 + co],
                     tile[(m4 * 4 + 2) * 65 + co],
                     tile[(m4 * 4 + 3) * 65 + co] };
        *(float4*)(out + ((size_t)(n * 256 + cog * 64 + co) * 784 + mq * 196 + m4 * 4)) = v;
    }
}

extern "C" void kernel_launch(void* const* d_in, const int* in_sizes, int n_in,
                              void* d_out, int out_size, void* d_ws, size_t ws_size,
                              hipStream_t stream) {
    const float* x       = (const float*)d_in[0];
    const float* w_yat   = (const float*)d_in[1];
    const float* alpha   = (const float*)d_in[2];
    const float* w_lin   = (const float*)d_in[3];
    const float* w_short = (const float*)d_in[4];
    float* out = (float*)d_out;
    float* wsf = (float*)d_ws;

    U16* xt  = (U16*)((char*)d_ws + U16_BYTE_OFF);
    U16* yb  = xt + (size_t)N_ * H_ * W_ * CIN;       // 12,845,056 U16 (= 2 x OUTSZ)
    U16* B1  = yb + (size_t)OUTSZ;                    // +6,422,528
    U16* B2  = B1 + 1152 * COUT;                      // +294,912
    U16* B3  = B2 + CIN * COUT;                       // +32,768
    U16* pid = B3 + 2304 * COUT;                      // +589,824
    U16* p23 = pid + (size_t)OUTSZ;                   // +6,422,528 (NS=4 lin partials)
    float* s2 = (float*)p23;                          // 401 KB, dead before k_lin writes p23

    size_t need4 = (size_t)U16_BYTE_OFF +
                   2 * ((size_t)(p23 - xt) + 2 * (size_t)OUTSZ);
    bool four = ws_size >= need4;

    k_prep<<<5408, 256, 0, stream>>>(x, w_yat, w_lin, w_short, alpha, xt, B1, B3, B2, wsf, s2);
    k_yat <<<392, 256, 0, stream>>>(xt, B1, B2, wsf, s2, yb, pid);

    if (four) {
        k_lin<4><<<1568, 256, 0, stream>>>(yb, B3, pid, xt, p23);  // p0,p1 alias xt
        k_red<4><<<512, 256, 0, stream>>>(xt, p23, out);
    } else {
        k_lin<2><<<784, 256, 0, stream>>>(yb, B3, pid, xt, nullptr);
        k_red<2><<<512, 256, 0, stream>>>(xt, nullptr, out);
    }
}